// Round 3
// baseline (386.022 us; speedup 1.0000x reference)
//
#include <hip/hip_runtime.h>
#include <hip/hip_bf16.h>
#include <cstdint>

#define B_ 16
#define N_ 1024
#define D_ 256
#define H_ 128

typedef unsigned short u16;
typedef __attribute__((ext_vector_type(8))) short bf16x8;
typedef __attribute__((ext_vector_type(4))) float f32x4;

__device__ __forceinline__ u16 f2bf(float f) {
    union { float f; uint32_t u; } v; v.f = f;
    return (u16)((v.u + 0x7FFFu + ((v.u >> 16) & 1u)) >> 16);  // RNE
}

typedef __attribute__((address_space(3))) void lds_void;
typedef const __attribute__((address_space(1))) void g_void;

__device__ __forceinline__ void gl_lds16(const void* g, void* l) {
    // async global->LDS, 16B/lane; LDS dest = wave-uniform base + lane*16
    __builtin_amdgcn_global_load_lds((g_void*)g, (lds_void*)l, 16, 0, 0);
}

// ---------------------------------------------------------------------------
// K1: fp32 adjacencies -> bf16 (normal + transposed copies). Run once.
// grid (N/32, N/32, B*2), block 256.
__global__ __launch_bounds__(256) void k_conv_adj(
    const float* __restrict__ dep, const float* __restrict__ lat,
    u16* __restrict__ depb, u16* __restrict__ latb,
    u16* __restrict__ depTb, u16* __restrict__ latTb)
{
    __shared__ float tile[32][33];
    const int bz = blockIdx.z;
    const int b = bz >> 1;
    const float* src = (bz & 1) ? lat : dep;
    u16* dstN = (bz & 1) ? latb : depb;
    u16* dstT = (bz & 1) ? latTb : depTb;
    const int r0 = blockIdx.y * 32, c0 = blockIdx.x * 32;
    const int t = threadIdx.x;
    const int r = t >> 3, cg = (t & 7) * 4;

    const float4 v = *(const float4*)(src + ((size_t)b * N_ + r0 + r) * N_ + c0 + cg);
    ushort4 nv;
    nv.x = f2bf(v.x); nv.y = f2bf(v.y); nv.z = f2bf(v.z); nv.w = f2bf(v.w);
    *(ushort4*)(dstN + ((size_t)b * N_ + r0 + r) * N_ + c0 + cg) = nv;

    tile[r][cg] = v.x; tile[r][cg + 1] = v.y; tile[r][cg + 2] = v.z; tile[r][cg + 3] = v.w;
    __syncthreads();

    const int orow = t >> 3, ii = (t & 7) * 4;  // out row = source col
    ushort4 tv;
    tv.x = f2bf(tile[ii][orow]);     tv.y = f2bf(tile[ii + 1][orow]);
    tv.z = f2bf(tile[ii + 2][orow]); tv.w = f2bf(tile[ii + 3][orow]);
    *(ushort4*)(dstT + ((size_t)b * N_ + c0 + orow) * N_ + r0 + ii) = tv;
}

// ---------------------------------------------------------------------------
// K2: per-layer refine gate + x transposed to bf16 [B, D, N].
// grid (N/32, B), block 256.
__global__ __launch_bounds__(256) void k_gate_xt(
    const float* __restrict__ x, const float* __restrict__ rg,
    float* __restrict__ gate, u16* __restrict__ xT)
{
    __shared__ u16 lx[D_][36];     // [d][n], pad to 36 for 8B-aligned rows
    __shared__ float srg[D_];
    const int b = blockIdx.y, n0 = blockIdx.x * 32;
    const int t = threadIdx.x;
    srg[t] = rg[t];
    __syncthreads();

    const int r = t >> 3, cg = t & 7;  // row r (0..31), 8 threads/row
    const float* xrow = x + ((size_t)b * N_ + n0 + r) * D_;
    float dot = 0.f;
    #pragma unroll
    for (int u = 0; u < 8; ++u) {
        const int c = cg * 32 + u * 4;
        const float4 v = *(const float4*)(xrow + c);
        lx[c][r] = f2bf(v.x); lx[c + 1][r] = f2bf(v.y);
        lx[c + 2][r] = f2bf(v.z); lx[c + 3][r] = f2bf(v.w);
        dot += v.x * srg[c] + v.y * srg[c + 1] + v.z * srg[c + 2] + v.w * srg[c + 3];
    }
    dot += __shfl_down(dot, 4, 8);
    dot += __shfl_down(dot, 2, 8);
    dot += __shfl_down(dot, 1, 8);
    if (cg == 0) gate[(size_t)b * N_ + n0 + r] = 1.f / (1.f + expf(-dot));
    __syncthreads();

    #pragma unroll
    for (int i = 0; i < 8; ++i) {
        const int unit = i * 256 + t;
        const int d = unit >> 3, nch = (unit & 7) * 4;
        ushort4 wv;
        wv.x = lx[d][nch];     wv.y = lx[d][nch + 1];
        wv.z = lx[d][nch + 2]; wv.w = lx[d][nch + 3];
        *(ushort4*)(xT + ((size_t)b * D_ + d) * N_ + n0 + nch) = wv;
    }
}

// ---------------------------------------------------------------------------
// K3: dual-A MFMA GEMM: Ax = g*(A1@x) + (1-g)*(A2@x), then gcn-gate + x.
// z=0: (dep,lat,Wgi,bgi)->axin ; z=1: (depT,latT,Wgo,bgo)->axout
// grid (N/32, B, 2), block 256 (4 waves). Tile 32 rows x 256 cols, BK=32.
__global__ __launch_bounds__(256) void k_gemm_ax(
    const u16* __restrict__ depb, const u16* __restrict__ latb,
    const u16* __restrict__ depTb, const u16* __restrict__ latTb,
    const u16* __restrict__ xT,
    const float* __restrict__ gate,
    const float* __restrict__ Wgi, const float* __restrict__ Wgo,
    const float* __restrict__ bgi, const float* __restrict__ bgo,
    const float* __restrict__ xcur,
    u16* __restrict__ axin, u16* __restrict__ axout)
{
    __shared__ __align__(16) char smem[33280];  // staging 20KB / epilogue 32x260 f32
    u16* sA1 = (u16*)smem;          // [32 m][32 k]
    u16* sA2 = sA1 + 1024;
    u16* sB  = sA2 + 1024;          // [256 n][32 k]
    float* hbuf = (float*)smem;     // epilogue alias: [32][260]
    __shared__ float sh_g[32];
    __shared__ float sh_s[32];

    const int b = blockIdx.y;
    const int m0 = blockIdx.x * 32;
    const int z = blockIdx.z;
    const u16* A1 = z ? depTb : depb;
    const u16* A2 = z ? latTb : latb;
    const float* Wg = z ? Wgo : Wgi;
    const float bg0 = z ? bgo[0] : bgi[0];
    u16* outp = z ? axout : axin;

    const int t = threadIdx.x;
    const int lane = t & 63;
    const int w = t >> 6;

    if (t < 32) sh_g[t] = gate[(size_t)b * N_ + m0 + t];

    f32x4 acc1[2][4], acc2[2][4];
    const f32x4 fz = {0.f, 0.f, 0.f, 0.f};
    #pragma unroll
    for (int i = 0; i < 2; ++i)
        #pragma unroll
        for (int j = 0; j < 4; ++j) { acc1[i][j] = fz; acc2[i][j] = fz; }

    // 20 x 1KB staging chunks, 5 per wave
    const u16* gsrc[5];
    u16* ldst[5];
    #pragma unroll
    for (int ci = 0; ci < 5; ++ci) {
        const int c = w * 5 + ci;
        const int el = lane * 8;
        if (c < 4) {
            const int cc = c & 1;
            const int e = cc * 512 + el;
            const int m = e >> 5, k = e & 31;
            const u16* base = (c < 2) ? A1 : A2;
            gsrc[ci] = base + ((size_t)b * N_ + m0 + m) * N_ + k;
            ldst[ci] = ((c < 2) ? sA1 : sA2) + cc * 512;
        } else {
            const int cc = c - 4;
            const int e = cc * 512 + el;
            const int n = e >> 5, k = e & 31;
            gsrc[ci] = xT + ((size_t)b * D_ + n) * N_ + k;
            ldst[ci] = sB + cc * 512;
        }
    }

    const int mrow = lane & 15;
    const int kg = (lane >> 4) * 8;

    for (int ks = 0; ks < N_ / 32; ++ks) {
        #pragma unroll
        for (int ci = 0; ci < 5; ++ci) gl_lds16(gsrc[ci], ldst[ci]);
        __syncthreads();
        bf16x8 a1[2], a2[2], fb[4];
        #pragma unroll
        for (int mt = 0; mt < 2; ++mt) {
            a1[mt] = *(const bf16x8*)(sA1 + (mt * 16 + mrow) * 32 + kg);
            a2[mt] = *(const bf16x8*)(sA2 + (mt * 16 + mrow) * 32 + kg);
        }
        #pragma unroll
        for (int nt = 0; nt < 4; ++nt)
            fb[nt] = *(const bf16x8*)(sB + (w * 64 + nt * 16 + mrow) * 32 + kg);
        #pragma unroll
        for (int mt = 0; mt < 2; ++mt)
            #pragma unroll
            for (int nt = 0; nt < 4; ++nt) {
                acc1[mt][nt] = __builtin_amdgcn_mfma_f32_16x16x32_bf16(a1[mt], fb[nt], acc1[mt][nt], 0, 0, 0);
                acc2[mt][nt] = __builtin_amdgcn_mfma_f32_16x16x32_bf16(a2[mt], fb[nt], acc2[mt][nt], 0, 0, 0);
            }
        __syncthreads();
        #pragma unroll
        for (int ci = 0; ci < 5; ++ci) gsrc[ci] += 32;
    }

    // epilogue: gate blend into hbuf (C layout: col=lane&15, row=(lane>>4)*4+reg)
    const int hi = lane >> 4;
    #pragma unroll
    for (int mt = 0; mt < 2; ++mt)
        #pragma unroll
        for (int nt = 0; nt < 4; ++nt) {
            const int col = w * 64 + nt * 16 + mrow;
            #pragma unroll
            for (int rr = 0; rr < 4; ++rr) {
                const int row = mt * 16 + hi * 4 + rr;
                const float g = sh_g[row];
                hbuf[row * 260 + col] = g * acc1[mt][nt][rr] + (1.f - g) * acc2[mt][nt][rr];
            }
        }
    __syncthreads();

    {   // per-row dot with Wg -> sigmoid
        const int rr = t >> 3;
        const int c0 = (t & 7) * 32;
        float dot = 0.f;
        #pragma unroll 8
        for (int u = 0; u < 32; ++u) dot += hbuf[rr * 260 + c0 + u] * Wg[c0 + u];
        dot += __shfl_down(dot, 4, 8);
        dot += __shfl_down(dot, 2, 8);
        dot += __shfl_down(dot, 1, 8);
        if ((t & 7) == 0) sh_s[rr] = 1.f / (1.f + expf(-dot));
    }
    __syncthreads();

    #pragma unroll
    for (int i = 0; i < 16; ++i) {
        const int row = (t >> 7) + i * 2;
        const int c = (t & 127) * 2;
        const float s = sh_s[row];
        const size_t gidx = ((size_t)b * N_ + m0 + row) * D_ + c;
        const float2 xv = *(const float2*)(xcur + gidx);
        const float v0 = hbuf[row * 260 + c] * s + bg0 + xv.x;
        const float v1 = hbuf[row * 260 + c + 1] * s + bg0 + xv.y;
        *(ushort2*)(outp + gidx) = make_ushort2(f2bf(v0), f2bf(v1));
    }
}

// ---------------------------------------------------------------------------
// K4: h = [axin@Wi^T + 2bi, axout@Wo^T + 2bo]; LayerNorm; exact GELU.
// Output is ALWAYS fp32 (reference output dtype is float32).
// grid (N/32, B), block 256. Waves 0,1 -> in-half; 2,3 -> out-half.
__global__ __launch_bounds__(256) void k_fc_ln(
    const u16* __restrict__ axin, const u16* __restrict__ axout,
    const u16* __restrict__ Wib, const u16* __restrict__ Wob,
    const float* __restrict__ bi, const float* __restrict__ bo,
    const float* __restrict__ lg, const float* __restrict__ lb,
    float* __restrict__ outp)
{
    __shared__ __align__(16) char smem[33280];
    u16* sAin = (u16*)smem;         // [32][32]
    u16* sAout = sAin + 1024;
    u16* sWi = sAout + 1024;        // [128][32]
    u16* sWo = sWi + 4096;
    float* hbuf = (float*)smem;     // epilogue alias [32][260]
    __shared__ float sh_mu[32], sh_rs[32];

    const int b = blockIdx.y, m0 = blockIdx.x * 32;
    const int t = threadIdx.x, lane = t & 63, w = t >> 6;
    const int half = w >> 1, wn = w & 1;

    f32x4 acc[2][4];
    const f32x4 fz = {0.f, 0.f, 0.f, 0.f};
    #pragma unroll
    for (int i = 0; i < 2; ++i)
        #pragma unroll
        for (int j = 0; j < 4; ++j) acc[i][j] = fz;

    const u16* gsrc[5];
    u16* ldst[5];
    #pragma unroll
    for (int ci = 0; ci < 5; ++ci) {
        const int c = w * 5 + ci;
        const int el = lane * 8;
        if (c < 4) {
            const int cc = c & 1;
            const int e = cc * 512 + el;
            const int m = e >> 5, k = e & 31;
            const u16* base = (c < 2) ? axin : axout;
            gsrc[ci] = base + ((size_t)b * N_ + m0 + m) * D_ + k;
            ldst[ci] = ((c < 2) ? sAin : sAout) + cc * 512;
        } else {
            const int cc = (c - 4) & 7;
            const int e = cc * 512 + el;
            const int n = e >> 5, k = e & 31;
            const u16* base = (c < 12) ? Wib : Wob;
            gsrc[ci] = base + (size_t)n * D_ + k;
            ldst[ci] = ((c < 12) ? sWi : sWo) + cc * 512;
        }
    }

    const u16* sA = half ? sAout : sAin;
    const u16* sW = half ? sWo : sWi;
    const int mrow = lane & 15;
    const int kg = (lane >> 4) * 8;

    for (int ks = 0; ks < D_ / 32; ++ks) {
        #pragma unroll
        for (int ci = 0; ci < 5; ++ci) gl_lds16(gsrc[ci], ldst[ci]);
        __syncthreads();
        bf16x8 a[2], fb[4];
        #pragma unroll
        for (int mt = 0; mt < 2; ++mt)
            a[mt] = *(const bf16x8*)(sA + (mt * 16 + mrow) * 32 + kg);
        #pragma unroll
        for (int nt = 0; nt < 4; ++nt)
            fb[nt] = *(const bf16x8*)(sW + (wn * 64 + nt * 16 + mrow) * 32 + kg);
        #pragma unroll
        for (int mt = 0; mt < 2; ++mt)
            #pragma unroll
            for (int nt = 0; nt < 4; ++nt)
                acc[mt][nt] = __builtin_amdgcn_mfma_f32_16x16x32_bf16(a[mt], fb[nt], acc[mt][nt], 0, 0, 0);
        __syncthreads();
        #pragma unroll
        for (int ci = 0; ci < 5; ++ci) gsrc[ci] += 32;
    }

    const int hi = lane >> 4;
    #pragma unroll
    for (int mt = 0; mt < 2; ++mt)
        #pragma unroll
        for (int nt = 0; nt < 4; ++nt) {
            const int colh = wn * 64 + nt * 16 + mrow;     // 0..127 within half
            const int col = half * 128 + colh;
            const float bias = 2.f * (half ? bo[colh] : bi[colh]);
            #pragma unroll
            for (int rr = 0; rr < 4; ++rr) {
                const int row = mt * 16 + hi * 4 + rr;
                hbuf[row * 260 + col] = acc[mt][nt][rr] + bias;
            }
        }
    __syncthreads();

    {   // LN stats per row
        const int rr = t >> 3;
        const int c0 = (t & 7) * 32;
        float s = 0.f, ss = 0.f;
        #pragma unroll 8
        for (int u = 0; u < 32; ++u) {
            const float v = hbuf[rr * 260 + c0 + u];
            s += v; ss += v * v;
        }
        s += __shfl_down(s, 4, 8);  ss += __shfl_down(ss, 4, 8);
        s += __shfl_down(s, 2, 8);  ss += __shfl_down(ss, 2, 8);
        s += __shfl_down(s, 1, 8);  ss += __shfl_down(ss, 1, 8);
        if ((t & 7) == 0) {
            const float mu = s * (1.f / 256.f);
            const float var = ss * (1.f / 256.f) - mu * mu;
            sh_mu[rr] = mu;
            sh_rs[rr] = rsqrtf(var + 1e-5f);
        }
    }
    __syncthreads();

    #pragma unroll
    for (int i = 0; i < 16; ++i) {
        const int row = (t >> 7) + i * 2;
        const int c = (t & 127) * 2;
        const float mu = sh_mu[row], rs = sh_rs[row];
        const float2 gg = *(const float2*)(lg + c);
        const float2 bb = *(const float2*)(lb + c);
        const float v0 = (hbuf[row * 260 + c] - mu) * rs * gg.x + bb.x;
        const float v1 = (hbuf[row * 260 + c + 1] - mu) * rs * gg.y + bb.y;
        const float y0 = 0.5f * v0 * (1.f + erff(v0 * 0.70710678118654752f));
        const float y1 = 0.5f * v1 * (1.f + erff(v1 * 0.70710678118654752f));
        const size_t gidx = ((size_t)b * N_ + m0 + row) * D_ + c;
        *(float2*)(outp + gidx) = make_float2(y0, y1);
    }
}

// ---------------------------------------------------------------------------
// tiny per-layer fp32->bf16 weight convert (H*D each)
__global__ __launch_bounds__(256) void k_convw(
    const float* __restrict__ wi, const float* __restrict__ wo,
    u16* __restrict__ wib, u16* __restrict__ wob)
{
    const int i = blockIdx.x * 256 + threadIdx.x;  // 32768 total
    wib[i] = f2bf(wi[i]);
    wob[i] = f2bf(wo[i]);
}

// ---------------------------------------------------------------------------
extern "C" void kernel_launch(void* const* d_in, const int* in_sizes, int n_in,
                              void* d_out, int out_size, void* d_ws, size_t ws_size,
                              hipStream_t stream)
{
    (void)in_sizes; (void)n_in; (void)out_size; (void)ws_size;

    const float* x0  = (const float*)d_in[0];
    const float* lat = (const float*)d_in[1];
    const float* dep = (const float*)d_in[2];
    const float* rg  = (const float*)d_in[3];   // [L,D,1]
    const float* Wgi = (const float*)d_in[4];   // [L,D,1]
    const float* bgi = (const float*)d_in[5];   // [L,1]
    const float* Wgo = (const float*)d_in[6];
    const float* bgo = (const float*)d_in[7];
    const float* fiW = (const float*)d_in[8];   // [L,H,D]
    const float* fib = (const float*)d_in[9];   // [L,H]
    const float* foW = (const float*)d_in[10];
    const float* fob = (const float*)d_in[11];
    const float* lng = (const float*)d_in[12];  // [L,2H]
    const float* lnb = (const float*)d_in[13];

    char* ws = (char*)d_ws;
    size_t off = 0;
    auto alloc = [&](size_t bytes) {
        char* p = ws + off;
        off += (bytes + 255) & ~(size_t)255;
        return p;
    };
    u16* depb  = (u16*)alloc(2ull * B_ * N_ * N_);
    u16* latb  = (u16*)alloc(2ull * B_ * N_ * N_);
    u16* depTb = (u16*)alloc(2ull * B_ * N_ * N_);
    u16* latTb = (u16*)alloc(2ull * B_ * N_ * N_);
    u16* xT    = (u16*)alloc(2ull * B_ * D_ * N_);
    u16* axin  = (u16*)alloc(2ull * B_ * N_ * D_);
    u16* axout = (u16*)alloc(2ull * B_ * N_ * D_);
    float* gate = (float*)alloc(4ull * B_ * N_);
    float* xbuf = (float*)alloc(4ull * B_ * N_ * D_);
    u16* Wib = (u16*)alloc(2ull * H_ * D_);
    u16* Wob = (u16*)alloc(2ull * H_ * D_);

    k_conv_adj<<<dim3(32, 32, 32), 256, 0, stream>>>(dep, lat, depb, latb, depTb, latTb);

    const float* xcur = x0;
    for (int l = 0; l < 2; ++l) {
        k_convw<<<128, 256, 0, stream>>>(fiW + (size_t)l * H_ * D_, foW + (size_t)l * H_ * D_, Wib, Wob);
        k_gate_xt<<<dim3(32, B_), 256, 0, stream>>>(xcur, rg + l * D_, gate, xT);
        k_gemm_ax<<<dim3(32, B_, 2), 256, 0, stream>>>(
            depb, latb, depTb, latTb, xT, gate,
            Wgi + l * D_, Wgo + l * D_, bgi + l, bgo + l,
            xcur, axin, axout);
        const bool last = (l == 1);
        k_fc_ln<<<dim3(32, B_), 256, 0, stream>>>(
            axin, axout, Wib, Wob,
            fib + l * H_, fob + l * H_,
            lng + l * 2 * H_, lnb + l * 2 * H_,
            last ? (float*)d_out : xbuf);
        xcur = xbuf;
    }
}